// Round 3
// baseline (1061.253 us; speedup 1.0000x reference)
//
#include <hip/hip_runtime.h>

#define DT 0.1f

typedef float v2f __attribute__((ext_vector_type(2)));

// Pack per-hidden-unit weights into one float4: (W1[0][j], W1[1][j], b1[j], W2[j])
__global__ void pack_weights(const float* __restrict__ W1, const float* __restrict__ b1,
                             const float* __restrict__ W2, float4* __restrict__ ws, int hidden) {
    int j = blockIdx.x * blockDim.x + threadIdx.x;
    if (j < hidden) {
        ws[j] = make_float4(W1[j], W1[hidden + j], b1[j], W2[j]);
    }
}

// Guaranteed packed fp32 FMA (2 lanes per instruction slot).
__device__ __forceinline__ v2f pk_fma(v2f a, v2f b, v2f c) {
    v2f d;
    asm("v_pk_fma_f32 %0, %1, %2, %3" : "=v"(d) : "v"(a), "v"(b), "v"(c));
    return d;
}

// DPP-based add-reduce (VALU pipe). 0xB1=xor1, 0x4E=xor2, 0x141=half-mirror (8-lane groups).
template <int CTRL>
__device__ __forceinline__ float dpp_add(float x) {
    int v = __builtin_amdgcn_mov_dpp(__float_as_int(x), CTRL, 0xf, 0xf, true);
    return x + __int_as_float(v);
}

// 8 lanes per element: p = lane & 7 owns hidden units [p*32, (p+1)*32).
__global__ __launch_bounds__(256) void waterbalance(
    const float* __restrict__ inflows, const float* __restrict__ storage0,
    const float4* __restrict__ ws, const float* __restrict__ b2,
    float* __restrict__ out_storages, float* __restrict__ out_outflows,
    int iters, int batch)
{
    const int tid = blockIdx.x * blockDim.x + threadIdx.x;
    const int e = tid >> 3;      // element index
    const int p = tid & 7;       // unit-group within element
    if (e >= batch) return;

    // This lane's 32 units' weights, packed as float2 pairs: 64 v2f = 128 VGPRs.
    v2f wx[16], wy[16], wb[16], w2[16];
    #pragma unroll
    for (int r = 0; r < 16; ++r) {
        float4 a = ws[p * 32 + 2 * r];
        float4 b = ws[p * 32 + 2 * r + 1];
        wx[r] = (v2f){a.x, b.x};
        wy[r] = (v2f){a.y, b.y};
        wb[r] = (v2f){a.z, b.z};
        w2[r] = (v2f){a.w, b.w};
    }
    // Make the weight values opaque so the compiler CANNOT sink the loads into
    // the time loop (round 2: VGPR_Count=84 proved it reloaded from L1 every step).
    #pragma unroll
    for (int r = 0; r < 16; ++r) {
        asm("" : "+v"(wx[r]), "+v"(wy[r]), "+v"(wb[r]), "+v"(w2[r]));
    }

    const float b2v = b2[0];

    float s = storage0[e];
    if (p == 0) out_storages[e] = s;     // storages[0] = storage0

    const float* __restrict__ inp = inflows + e;
    float* __restrict__ po = out_outflows + e;                    // row t
    float* __restrict__ ps = out_storages + (size_t)batch + e;    // row t+1

    const int nchunk = iters >> 3;
    const int tail_start = nchunk << 3;

    // Prefetch chunk 0 (8 steps of inflow; 8 in-flight loads -> ~1600cy latency budget).
    float buf[8];
    #pragma unroll
    for (int r = 0; r < 8; ++r) buf[r] = inp[(size_t)r * batch];

    for (int c = 0; c < nchunk; ++c) {
        float nb[8];
        if (c + 1 < nchunk) {
            const float* q = inp + (size_t)(c + 1) * 8 * batch;
            #pragma unroll
            for (int r = 0; r < 8; ++r) nb[r] = q[(size_t)r * batch];
        } else {
            #pragma unroll
            for (int r = 0; r < 8; ++r) nb[r] = 0.0f;
        }

        #pragma unroll
        for (int r = 0; r < 8; ++r) {
            const float inflow = buf[r];
            const v2f in2 = (v2f){inflow, inflow};
            const v2f s2  = (v2f){s, s};
            const v2f zero2 = (v2f)(0.0f);
            v2f acc0 = (v2f)(0.0f);
            v2f acc1 = (v2f)(0.0f);

            #pragma unroll
            for (int g = 0; g < 16; g += 2) {
                v2f z0 = pk_fma(in2, wx[g], pk_fma(s2, wy[g], wb[g]));
                z0 = __builtin_elementwise_max(z0, zero2);
                acc0 = pk_fma(z0, w2[g], acc0);

                v2f z1 = pk_fma(in2, wx[g + 1], pk_fma(s2, wy[g + 1], wb[g + 1]));
                z1 = __builtin_elementwise_max(z1, zero2);
                acc1 = pk_fma(z1, w2[g + 1], acc1);
            }

            float part = (acc0.x + acc1.x) + (acc0.y + acc1.y);
            part = dpp_add<0xB1>(part);    // xor 1
            part = dpp_add<0x4E>(part);    // xor 2
            part = dpp_add<0x141>(part);   // fold the two quads of the 8-lane group
            const float outflow = part + b2v;

            s = fmaf(DT, inflow - outflow, s);   // identical in all 8 lanes

            if (p == 0) {
                *po = outflow;
                *ps = s;
            }
            po += batch;
            ps += batch;
        }

        #pragma unroll
        for (int r = 0; r < 8; ++r) buf[r] = nb[r];
    }

    // Tail for iters % 8 != 0 (dead for iters=512, kept for generality).
    for (int t = tail_start; t < iters; ++t) {
        const float inflow = inp[(size_t)t * batch];
        const v2f in2 = (v2f){inflow, inflow};
        const v2f s2  = (v2f){s, s};
        const v2f zero2 = (v2f)(0.0f);
        v2f acc0 = (v2f)(0.0f), acc1 = (v2f)(0.0f);
        #pragma unroll
        for (int g = 0; g < 16; g += 2) {
            v2f z0 = pk_fma(in2, wx[g], pk_fma(s2, wy[g], wb[g]));
            z0 = __builtin_elementwise_max(z0, zero2);
            acc0 = pk_fma(z0, w2[g], acc0);
            v2f z1 = pk_fma(in2, wx[g + 1], pk_fma(s2, wy[g + 1], wb[g + 1]));
            z1 = __builtin_elementwise_max(z1, zero2);
            acc1 = pk_fma(z1, w2[g + 1], acc1);
        }
        float part = (acc0.x + acc1.x) + (acc0.y + acc1.y);
        part = dpp_add<0xB1>(part);
        part = dpp_add<0x4E>(part);
        part = dpp_add<0x141>(part);
        const float outflow = part + b2v;
        s = fmaf(DT, inflow - outflow, s);
        if (p == 0) {
            *po = outflow;
            *ps = s;
        }
        po += batch;
        ps += batch;
    }
}

extern "C" void kernel_launch(void* const* d_in, const int* in_sizes, int n_in,
                              void* d_out, int out_size, void* d_ws, size_t ws_size,
                              hipStream_t stream) {
    const float* inflows  = (const float*)d_in[0];
    const float* storage0 = (const float*)d_in[1];
    const float* W1       = (const float*)d_in[2];
    const float* b1       = (const float*)d_in[3];
    const float* W2       = (const float*)d_in[4];
    const float* b2       = (const float*)d_in[5];

    int batch  = in_sizes[1];                 // 65536
    int iters  = in_sizes[0] / batch;         // 512
    int hidden = in_sizes[3];                 // 256

    float4* ws = (float4*)d_ws;
    pack_weights<<<(hidden + 255) / 256, 256, 0, stream>>>(W1, b1, W2, ws, hidden);

    float* out_storages = (float*)d_out;                                // (iters+1, batch)
    float* out_outflows = out_storages + (size_t)(iters + 1) * batch;   // (iters, batch)

    int threads = batch * 8;
    waterbalance<<<(threads + 255) / 256, 256, 0, stream>>>(
        inflows, storage0, ws, b2, out_storages, out_outflows, iters, batch);
}